// Round 3
// baseline (157.638 us; speedup 1.0000x reference)
//
#include <hip/hip_runtime.h>
#include <stdint.h>

typedef float v2f __attribute__((ext_vector_type(2)));

#define ALPHA_C 1000.0f
#define EPS_C 1e-6f
#define NPTS 8192
#define BATCH 4
#define QPT 8                               // queries per thread (4 packed pairs)
#define TPB 256
#define SLICES 64
#define CAND_PER_SLICE (NPTS / SLICES)      // 128
#define QCHUNK (TPB * QPT)                  // 2048
#define NQCHUNKS (NPTS / QCHUNK)            // 4
#define TOTQ (2 * BATCH * NPTS)             // 65536
#define NN_BLOCKS (2 * BATCH * NQCHUNKS * SLICES)  // 2048
#define RED_BLOCKS (TOTQ / TPB)             // 256

// ---------------------------------------------------------------------------
// Kernel A: brute-force NN argmax of s = x·y - 0.5*yy + 2 (<=> argmin dist),
// packed fp32 query pairs. Cross-slice merge via atomicMax on
// (s_bits<<32 | ~idx); ~idx => ties prefer smaller index (jnp.argmin).
// ---------------------------------------------------------------------------
__global__ __launch_bounds__(TPB) void nn_kernel(
    const float* __restrict__ x, const float* __restrict__ y,
    unsigned long long* __restrict__ best) {
  int bid = blockIdx.x;
  int slice = bid & (SLICES - 1);
  int qc = (bid >> 6) & (NQCHUNKS - 1);
  int b = (bid >> 8) & (BATCH - 1);
  int dir = bid >> 10;

  const float* qp = (dir == 0 ? x : y) + b * NPTS * 3;
  const float* cp = (dir == 0 ? y : x) + b * NPTS * 3;
  unsigned long long* bq = best + (dir * BATCH + b) * NPTS;

  __shared__ float4 tile[CAND_PER_SLICE];
  int tid = threadIdx.x;
  if (tid < CAND_PER_SLICE) {
    int c = slice * CAND_PER_SLICE + tid;
    float cx = cp[c * 3 + 0], cy = cp[c * 3 + 1], cz = cp[c * 3 + 2];
    tile[tid] =
        make_float4(cx, cy, cz, 2.0f - 0.5f * (cx * cx + cy * cy + cz * cz));
  }
  __syncthreads();

  v2f axp[QPT / 2], ayp[QPT / 2], azp[QPT / 2], sbp[QPT / 2];
  int ib[QPT];
  int qbase = qc * QCHUNK + tid;
#pragma unroll
  for (int p = 0; p < QPT / 2; p++) {
    int q0 = qbase + (2 * p) * TPB;
    int q1 = qbase + (2 * p + 1) * TPB;
    axp[p] = (v2f){qp[q0 * 3 + 0], qp[q1 * 3 + 0]};
    ayp[p] = (v2f){qp[q0 * 3 + 1], qp[q1 * 3 + 1]};
    azp[p] = (v2f){qp[q0 * 3 + 2], qp[q1 * 3 + 2]};
    sbp[p] = (v2f){0.0f, 0.0f};  // s >= 0.5 always, so first cand wins
    ib[2 * p] = 0;
    ib[2 * p + 1] = 0;
  }

#pragma unroll 4
  for (int m = 0; m < CAND_PER_SLICE; m++) {
    float4 c = tile[m];
    v2f cx = {c.x, c.x}, cy = {c.y, c.y}, cz = {c.z, c.z}, cw = {c.w, c.w};
#pragma unroll
    for (int p = 0; p < QPT / 2; p++) {
      v2f t = __builtin_elementwise_fma(axp[p], cx, cw);
      t = __builtin_elementwise_fma(ayp[p], cy, t);
      t = __builtin_elementwise_fma(azp[p], cz, t);
      // strict > keeps first (smallest-index) max -> jnp.argmin tie semantics
      if (t.x > sbp[p].x) ib[2 * p] = m;
      if (t.y > sbp[p].y) ib[2 * p + 1] = m;
      sbp[p] = __builtin_elementwise_max(sbp[p], t);
    }
  }

  int cbase = slice * CAND_PER_SLICE;
#pragma unroll
  for (int p = 0; p < QPT / 2; p++) {
    unsigned long long k0 =
        ((unsigned long long)__float_as_uint(sbp[p].x) << 32) |
        (unsigned long long)(unsigned int)(~(cbase + ib[2 * p]));
    unsigned long long k1 =
        ((unsigned long long)__float_as_uint(sbp[p].y) << 32) |
        (unsigned long long)(unsigned int)(~(cbase + ib[2 * p + 1]));
    atomicMax(bq + qbase + (2 * p) * TPB, k0);
    atomicMax(bq + qbase + (2 * p + 1) * TPB, k1);
  }
}

// ---------------------------------------------------------------------------
// Kernel B (postA): per query, exact d for the winner (reference fp ordering),
// scatter exp(-alpha*d) into expsum[idx] and 1 into counts[idx].
// Regrouping: sum_q exp(-d_q)/(cnt[idx_q]+eps) == sum_c expsum[c]/(cnt[c]+eps)
// ---------------------------------------------------------------------------
__global__ __launch_bounds__(TPB) void postA_kernel(
    const float* __restrict__ x, const float* __restrict__ y,
    const unsigned long long* __restrict__ best,
    unsigned int* __restrict__ counts, float* __restrict__ expsum) {
  int i = blockIdx.x * blockDim.x + threadIdx.x;
  int q = i & (NPTS - 1);
  int db = i >> 13;
  int b = db & (BATCH - 1);
  int dir = db >> 2;
  const float* qp = (dir == 0 ? x : y) + b * NPTS * 3;
  const float* cp = (dir == 0 ? y : x) + b * NPTS * 3;

  unsigned int idx = ~(unsigned int)(best[i] & 0xFFFFFFFFull);

  float axv = qp[q * 3 + 0], ayv = qp[q * 3 + 1], azv = qp[q * 3 + 2];
  float bxv = cp[idx * 3 + 0], byv = cp[idx * 3 + 1], bzv = cp[idx * 3 + 2];
  float xx = axv * axv + ayv * ayv + azv * azv;
  float yy = bxv * bxv + byv * byv + bzv * bzv;
  float xy = axv * bxv + ayv * byv + azv * bzv;
  float d = xx - 2.0f * xy + yy;

  int base = db << 13;
  atomicAdd(expsum + base + idx, expf(-d * ALPHA_C));
  atomicAdd(counts + base + idx, 1u);
}

// ---------------------------------------------------------------------------
// Kernel C (postB): total = sum_c expsum[c]/(cnt[c]+eps); last block writes
// out = 1 - total/65536. Device-scope atomics + threadfence for the merge.
// ---------------------------------------------------------------------------
__global__ __launch_bounds__(TPB) void postB_kernel(
    const unsigned int* __restrict__ counts, const float* __restrict__ expsum,
    float* __restrict__ accum, unsigned int* __restrict__ done,
    float* __restrict__ out) {
  int i = blockIdx.x * blockDim.x + threadIdx.x;
  float v = expsum[i] / ((float)counts[i] + EPS_C);
#pragma unroll
  for (int o = 32; o > 0; o >>= 1) v += __shfl_down(v, o);
  if ((threadIdx.x & 63) == 0) atomicAdd(accum, v);
  __syncthreads();
  if (threadIdx.x == 0) {
    __threadfence();
    unsigned int t = atomicAdd(done, 1u);
    if (t == RED_BLOCKS - 1) {
      float total = atomicAdd(accum, 0.0f);  // L2 read-after-fence
      out[0] = 1.0f - total * (1.0f / (float)TOTQ);
    }
  }
}

extern "C" void kernel_launch(void* const* d_in, const int* in_sizes, int n_in,
                              void* d_out, int out_size, void* d_ws,
                              size_t ws_size, hipStream_t stream) {
  const float* x = (const float*)d_in[0];
  const float* y = (const float*)d_in[1];
  float* out = (float*)d_out;

  // ws: [best 8B][counts 4B][expsum 4B] x TOTQ, then accum(4) done(4)
  char* p = (char*)d_ws;
  unsigned long long* best = (unsigned long long*)p;
  unsigned int* counts = (unsigned int*)(p + (size_t)TOTQ * 8);
  float* expsum = (float*)(p + (size_t)TOTQ * 12);
  float* accum = (float*)(p + (size_t)TOTQ * 16);
  unsigned int* done = (unsigned int*)(p + (size_t)TOTQ * 16 + 4);

  hipMemsetAsync(d_ws, 0, (size_t)TOTQ * 16 + 8, stream);

  nn_kernel<<<NN_BLOCKS, TPB, 0, stream>>>(x, y, best);
  postA_kernel<<<TOTQ / TPB, TPB, 0, stream>>>(x, y, best, counts, expsum);
  postB_kernel<<<RED_BLOCKS, TPB, 0, stream>>>(counts, expsum, accum, done,
                                               out);
}